// Round 6
// baseline (2094.857 us; speedup 1.0000x reference)
//
#include <hip/hip_runtime.h>

// ECGLSTM: B=256, T=5000, input_size=1, H=64, fused FC(64->128)+ReLU.
// R6 = R5 + __launch_bounds__(256, 1).
// R5's VGPR_Count=48 proved the compiler SANK the W_hh loads into the
// timestep loop (targeting high occupancy it refused to hold 64 weight
// VGPRs, rematerializing the loads instead) -> every step paid global-load
// latency and the barrier's vmcnt(0) drain serialized it. We only ever run
// 4 waves on 4 SIMDs (1 block/CU, grid=256=CU count), so min-1-wave/EU is
// free and raises the VGPR budget to ~512: weights stay resident.
// Structure: block=256 (4 waves)/batch element; thread tid owns gate tid.
// - c/h update replicated in all 4 waves (each wave writes full h; reads
//   only its own writes -> lgkmcnt-ordered, no barrier needed for h).
// - ONE barrier/step (gates exchange), double-buffered gates+h.
// - v_pk_fma_f32 tied-accumulator dot product: 32 packed FMA/step.
// - x row staged to LDS once (20 KB): zero global loads in the loop.
// - Activation arithmetic identical to R1/R5 (absmax 3.8e-6).

#define LSTM_H 64
#define LSTM_T 5000
#define LSTM_B 256

typedef float v2f __attribute__((ext_vector_type(2)));

__device__ __forceinline__ void pk_fma_acc(v2f& acc, v2f a, v2f b) {
    // acc = a*b + acc, accumulate in place (tied operand -> no v_mov)
    asm("v_pk_fma_f32 %0, %1, %2, %0" : "+v"(acc) : "v"(a), "v"(b));
}

__device__ __forceinline__ float fast_rcp(float v) {
    return __builtin_amdgcn_rcpf(v);
}

__global__ __launch_bounds__(256, 1) void ECGLSTM_lstm_fused(
    const float* __restrict__ x,      // [B, T]
    const float* __restrict__ W_ih,   // [4H, 1]
    const float* __restrict__ W_hh,   // [4H, H]
    const float* __restrict__ b_ih,   // [4H]
    const float* __restrict__ b_hh,   // [4H]
    const float* __restrict__ W_fc,   // [128, H]
    const float* __restrict__ b_fc,   // [128]
    float* __restrict__ out)          // [B, 128]
{
    const int tid  = threadIdx.x;     // gate index 0..255
    const int lane = tid & 63;        // hidden unit this thread updates
    const int b    = blockIdx.x;

    __shared__ float xch[LSTM_T];             // whole x row, staged once
    __shared__ float hbuf[2][LSTM_H];         // double-buffered h
    __shared__ float gbuf[2][4 * LSTM_H];     // double-buffered gates

    // Stage x (coalesced, once)
    const float* xb = x + b * LSTM_T;
    for (int i = tid; i < LSTM_T; i += 256) xch[i] = xb[i];

    // W_hh row `tid` -> 32 v2f (64 VGPRs, resident thanks to launch_bounds)
    v2f w[LSTM_H / 2];
    {
        const float4* wrow = reinterpret_cast<const float4*>(W_hh + tid * LSTM_H);
        #pragma unroll
        for (int i = 0; i < LSTM_H / 4; ++i) {
            float4 v = wrow[i];
            w[2 * i]     = v2f{v.x, v.y};
            w[2 * i + 1] = v2f{v.z, v.w};
        }
    }
    const float wih  = W_ih[tid];
    const float bias = b_ih[tid] + b_hh[tid];
    const bool  is_tanh = ((tid >> 6) == 2);   // wave-uniform branch

    float c = 0.0f;                   // replicated: lane j of every wave has c[j]
    hbuf[0][lane] = 0.0f;             // every wave writes full h0 (identical values)
    __syncthreads();                  // x staged + h0 visible

    // One LSTM step at parity P: read hbuf[P]/gbuf[P], write hbuf[1-P].
    #define LSTM_STEP(t, P)                                                    \
    {                                                                          \
        const float xv = xch[(t)];                      /* broadcast b32 */    \
        v2f A = {0.f, 0.f}, C = {0.f, 0.f};                                    \
        const float4* h4 = reinterpret_cast<const float4*>(hbuf[(P)]);         \
        _Pragma("unroll")                                                      \
        for (int i = 0; i < LSTM_H / 4; ++i) {                                 \
            float4 hv = h4[i];                          /* b128 broadcast */   \
            pk_fma_acc(A, v2f{hv.x, hv.y}, w[2 * i]);                          \
            pk_fma_acc(C, v2f{hv.z, hv.w}, w[2 * i + 1]);                      \
        }                                                                      \
        float g = fmaf(xv, wih, bias) + ((A.x + A.y) + (C.x + C.y));           \
        float act;                                                             \
        if (is_tanh) {                                                         \
            float e = __expf(2.0f * g);                                        \
            act = 1.0f - 2.0f * fast_rcp(e + 1.0f);                            \
        } else {                                                               \
            float e = __expf(-g);                                              \
            act = fast_rcp(1.0f + e);                                          \
        }                                                                      \
        gbuf[(P)][tid] = act;                                                  \
        __syncthreads();                                /* the ONE barrier */  \
        const float ig = gbuf[(P)][lane];                                      \
        const float fg = gbuf[(P)][LSTM_H + lane];                             \
        const float gg = gbuf[(P)][2 * LSTM_H + lane];                         \
        const float og = gbuf[(P)][3 * LSTM_H + lane];                         \
        c = fmaf(fg, c, ig * gg);                                              \
        float e2 = __expf(2.0f * c);                                           \
        float th = 1.0f - 2.0f * fast_rcp(e2 + 1.0f);                          \
        hbuf[1 - (P)][lane] = og * th;                  /* all waves, same */  \
    }

    for (int t = 0; t < LSTM_T; t += 2) {
        LSTM_STEP(t, 0);
        LSTM_STEP(t + 1, 1);
    }
    #undef LSTM_STEP

    // Final h is in hbuf[0] (T even); each wave wrote it itself -> no barrier.
    // FC(64->128)+ReLU: threads 0..127 compute one output row each.
    if (tid < 128) {
        float s = b_fc[tid];
        const float4* wf = reinterpret_cast<const float4*>(W_fc + tid * LSTM_H);
        const float4* h4 = reinterpret_cast<const float4*>(hbuf[0]);
        #pragma unroll
        for (int i = 0; i < LSTM_H / 4; ++i) {
            float4 wv = wf[i];
            float4 hv = h4[i];
            s = fmaf(hv.x, wv.x, s);
            s = fmaf(hv.y, wv.y, s);
            s = fmaf(hv.z, wv.z, s);
            s = fmaf(hv.w, wv.w, s);
        }
        out[b * 128 + tid] = fmaxf(s, 0.0f);
    }
}

extern "C" void kernel_launch(void* const* d_in, const int* in_sizes, int n_in,
                              void* d_out, int out_size, void* d_ws, size_t ws_size,
                              hipStream_t stream) {
    const float* x    = (const float*)d_in[0];
    const float* W_ih = (const float*)d_in[1];
    const float* W_hh = (const float*)d_in[2];
    const float* b_ih = (const float*)d_in[3];
    const float* b_hh = (const float*)d_in[4];
    const float* W_fc = (const float*)d_in[5];
    const float* b_fc = (const float*)d_in[6];
    float* out = (float*)d_out;

    ECGLSTM_lstm_fused<<<LSTM_B, 256, 0, stream>>>(
        x, W_ih, W_hh, b_ih, b_hh, W_fc, b_fc, out);
}